// Round 6
// baseline (207.208 us; speedup 1.0000x reference)
//
#include <hip/hip_runtime.h>
#include <hip/hip_bf16.h>

// Winograd F(2x2,3x3) conv via split-bf16 MFMA. B=8,C=64,K=64 -> out 8x64x128x128 fp32.
// wg_u: U = GwG^T, split hi/lo bf16, d_ws in mfma-A-fragment-linear layout (256KB).
// wg_main: persistent block per CU (grid=256 = 8 img x 32 strips), 1024 thr (16 waves).
//   Each block sweeps 4 patches of 32 tiles (2x16); per patch 2 c-chunks of 32.
//   Pipeline: transform regs->LDS V (dbuf) -> barrier -> prefetch next chunk's x ->
//   GEMM (wave=xy, mfma_f32_16x16x32_bf16, D = UhVh+UhVl+UlVh) -> epilogue.
// R6: T 64->32 (acc 64->32 AGPR, kills R5 spill: WRITE 61MB w/ 33.5MB output),
//     persistent blocks + x-prefetch (R5 had none: MfmaUtil 8.6%, VALUBusy 16%),
//     all LDS patterns <=2-way banks (R5: 4.2M conflicts).

typedef __attribute__((ext_vector_type(8))) short short8;
typedef __attribute__((ext_vector_type(4))) float f32x4;

#define CPAD 36
#define VBUF 18432                  // floats per chunk buffer: 16*32*36
#define LDS_BYTES (2*VBUF*4)        // 147456 B

__device__ __forceinline__ unsigned short f2bf(float f) {
    unsigned u = __float_as_uint(f);
    unsigned r = (u + 0x7FFF + ((u >> 16) & 1)) >> 16;   // RNE
    return (unsigned short)r;
}

// U frag layout: f = ((xy*2+ks)*4+mt)*2+hl ; ushort[f*512 + lane*8 + j]
// A-frag lane l holds U[k = mt*16 + (l&15)][c = ks*32 + ((l>>4)&3)*8 + j]
__global__ void wg_u(const float* __restrict__ w, unsigned short* __restrict__ Uf) {
    int tid = blockIdx.x * blockDim.x + threadIdx.x;  // 4096 = K*C
    int k = tid & 63, c = tid >> 6;
    const float* wp = w + (k * 64 + c) * 9;
    float g[9];
    #pragma unroll
    for (int i = 0; i < 9; ++i) g[i] = wp[i];
    float t[4][3];
    #pragma unroll
    for (int j = 0; j < 3; ++j) {
        t[0][j] = g[j];
        t[1][j] = 0.5f * (g[j] + g[3 + j] + g[6 + j]);
        t[2][j] = 0.5f * (g[j] - g[3 + j] + g[6 + j]);
        t[3][j] = g[6 + j];
    }
    const int ks   = c >> 5;
    const int mt   = k >> 4;
    const int lane = (k & 15) + 16 * ((c >> 3) & 3);
    const int j    = c & 7;
    #pragma unroll
    for (int xr = 0; xr < 4; ++xr) {
        float a = t[xr][0], b = t[xr][1], cc = t[xr][2];
        float u4[4] = { a, 0.5f * (a + b + cc), 0.5f * (a - b + cc), cc };
        #pragma unroll
        for (int yr = 0; yr < 4; ++yr) {
            int xy = xr * 4 + yr;
            float uv = u4[yr];
            unsigned short h = f2bf(uv);
            float hf = __uint_as_float(((unsigned)h) << 16);
            unsigned short l = f2bf(uv - hf);
            int fh = ((xy * 2 + ks) * 4 + mt) * 2;
            Uf[(fh + 0) * 512 + lane * 8 + j] = h;
            Uf[(fh + 1) * 512 + lane * 8 + j] = l;
        }
    }
}

// cvt 8 fp32 -> bf16 hi/lo frags (pair cvt -> v_cvt_pk_bf16_f32)
__device__ __forceinline__ void cvt_frag(f32x4 a, f32x4 b, short8& h8, short8& l8) {
    union { short8 s; unsigned u[4]; } H, L;
    float v0[4] = { a[0], a[2], b[0], b[2] };
    float v1[4] = { a[1], a[3], b[1], b[3] };
    #pragma unroll
    for (int p = 0; p < 4; ++p) {
        __hip_bfloat162 hb = __float22bfloat162_rn(make_float2(v0[p], v1[p]));
        unsigned hu; __builtin_memcpy(&hu, &hb, 4);
        float h0 = __uint_as_float(hu << 16);
        float h1 = __uint_as_float(hu & 0xFFFF0000u);
        __hip_bfloat162 lb = __float22bfloat162_rn(make_float2(v0[p] - h0, v1[p] - h1));
        unsigned lu; __builtin_memcpy(&lu, &lb, 4);
        H.u[p] = hu; L.u[p] = lu;
    }
    h8 = H.s; l8 = L.s;
}

__global__ __launch_bounds__(1024, 4) void wg_main(
    const float* __restrict__ x, const unsigned short* __restrict__ Uf,
    const float* __restrict__ bias, float* __restrict__ out)
{
    extern __shared__ float smem[];   // V dbuf [2][16 xy][32 t][36 c]; sM aliases buf0

    const int tid  = threadIdx.x;
    const int bx   = blockIdx.x;      // 256 = b(8) * strip(32)
    const int b    = bx >> 5;
    const int s    = bx & 31;

    const int wv   = tid >> 6;        // wave = xy in GEMM/epilogue
    const int lane = tid & 63;
    const int hi   = lane >> 4;       // 0..3
    const int l15  = lane & 15;

    // produce mapping: thread owns one (t,c) unit per chunk
    const int tn   = wv & 1;          // tile row 0..1
    const int cg   = wv >> 1;         // 0..7
    const int c_l  = cg * 4 + hi;     // 0..31 (c within chunk)
    const int t_p  = tn * 16 + l15;   // 0..31 (tile within patch)

    const int row_off = 4 * s + 2 * tn;   // input row origin of this tile row
    const float* X0 = x + ((size_t)(b * 64 + c_l) * 130 + row_off) * 130 + 2 * l15;
    // x ptr for chunk g (= 2p+ch): X0 + ch*32*16900 + p*32

    f32x4 acc[4][2];

    // prefetch g=0
    float2 dn[4][2];
    #pragma unroll
    for (int i = 0; i < 4; ++i) {
        dn[i][0] = *(const float2*)(X0 + i * 130);
        dn[i][1] = *(const float2*)(X0 + i * 130 + 2);
    }

    #pragma unroll 1
    for (int p = 0; p < 4; ++p) {
        #pragma unroll
        for (int mt = 0; mt < 4; ++mt)
            #pragma unroll
            for (int nt = 0; nt < 2; ++nt) acc[mt][nt] = f32x4{0.f, 0.f, 0.f, 0.f};

        #pragma unroll 1
        for (int ch = 0; ch < 2; ++ch) {
            float* Vb = smem + ch * VBUF;
            // ---- transform dn -> V (B^T d B) ----
            {
                float d[4][4];
                #pragma unroll
                for (int i = 0; i < 4; ++i) {
                    d[i][0] = dn[i][0].x; d[i][1] = dn[i][0].y;
                    d[i][2] = dn[i][1].x; d[i][3] = dn[i][1].y;
                }
                float s0[4], s1[4], s2[4], s3[4];
                #pragma unroll
                for (int j = 0; j < 4; ++j) {
                    s0[j] = d[0][j] - d[2][j];
                    s1[j] = d[1][j] + d[2][j];
                    s2[j] = d[2][j] - d[1][j];
                    s3[j] = d[1][j] - d[3][j];
                }
                const int vo = t_p * CPAD + c_l;
                #define VROW(X, R)                                    \
                    Vb[((X)*4+0)*1152 + vo] = R[0] - R[2];            \
                    Vb[((X)*4+1)*1152 + vo] = R[1] + R[2];            \
                    Vb[((X)*4+2)*1152 + vo] = R[2] - R[1];            \
                    Vb[((X)*4+3)*1152 + vo] = R[1] - R[3];
                VROW(0, s0) VROW(1, s1) VROW(2, s2) VROW(3, s3)
                #undef VROW
            }
            __syncthreads();
            // ---- prefetch chunk g+1 (overlaps GEMM) ----
            const int g = p * 2 + ch;
            if (g < 7) {
                const int gn = g + 1;
                const float* xp = X0 + (size_t)(gn & 1) * 540800 + (gn >> 1) * 32;
                #pragma unroll
                for (int i = 0; i < 4; ++i) {
                    dn[i][0] = *(const float2*)(xp + i * 130);
                    dn[i][1] = *(const float2*)(xp + i * 130 + 2);
                }
            }
            // ---- GEMM K-step: wave wv = xy; 24 mfma ----
            const unsigned short* Ab = Uf + ((size_t)((wv * 2 + ch) * 8)) * 512 + lane * 8;
            short8 ah[4], al[4];
            #pragma unroll
            for (int mt = 0; mt < 4; ++mt) {
                ah[mt] = *(const short8*)(Ab + (mt * 2 + 0) * 512);
                al[mt] = *(const short8*)(Ab + (mt * 2 + 1) * 512);
            }
            const float* Bb = Vb + wv * 1152 + l15 * CPAD + hi * 8;
            #pragma unroll
            for (int nt = 0; nt < 2; ++nt) {
                f32x4 p0 = *(const f32x4*)(Bb + nt * 16 * CPAD);
                f32x4 p1 = *(const f32x4*)(Bb + nt * 16 * CPAD + 4);
                short8 bhf, blf;
                cvt_frag(p0, p1, bhf, blf);
                #pragma unroll
                for (int mt = 0; mt < 4; ++mt) {
                    acc[mt][nt] = __builtin_amdgcn_mfma_f32_16x16x32_bf16(ah[mt], bhf, acc[mt][nt], 0, 0, 0);
                    acc[mt][nt] = __builtin_amdgcn_mfma_f32_16x16x32_bf16(ah[mt], blf, acc[mt][nt], 0, 0, 0);
                    acc[mt][nt] = __builtin_amdgcn_mfma_f32_16x16x32_bf16(al[mt], bhf, acc[mt][nt], 0, 0, 0);
                }
            }
        }

        // ---- epilogue: Y = A^T M A + bias via sM[16 xy][32 k][34 pad] in buf0 ----
        // (buf0's GEMM readers finished before the ch=1 barrier; writes disjoint from buf1)
        float* sM = smem;
        #pragma unroll 1
        for (int kcl = 0; kcl < 2; ++kcl) {
            #pragma unroll
            for (int mh = 0; mh < 2; ++mh)
                #pragma unroll
                for (int nt = 0; nt < 2; ++nt)
                    #pragma unroll
                    for (int r = 0; r < 4; ++r) {
                        const int k_l = mh * 16 + hi * 4 + r;
                        sM[wv * 1088 + k_l * 34 + nt * 16 + l15] = acc[kcl * 2 + mh][nt][r];
                    }
            __syncthreads();
            const int k_l2 = wv * 2 + (lane >> 5);
            const int t2   = lane & 31;
            float m[16];
            #pragma unroll
            for (int xy = 0; xy < 16; ++xy) m[xy] = sM[xy * 1088 + k_l2 * 34 + t2];
            float q0[4], q1[4];
            #pragma unroll
            for (int y = 0; y < 4; ++y) {
                q0[y] = m[y] + m[4 + y] + m[8 + y];
                q1[y] = m[4 + y] - m[8 + y] - m[12 + y];
            }
            const int k  = kcl * 32 + k_l2;
            const float bv = bias[k];
            const float y00 = q0[0] + q0[1] + q0[2] + bv;
            const float y01 = q0[1] - q0[2] - q0[3] + bv;
            const float y10 = q1[0] + q1[1] + q1[2] + bv;
            const float y11 = q1[1] - q1[2] - q1[3] + bv;
            const int tn2 = t2 >> 4, tm2 = t2 & 15;
            const int oh = 4 * s + 2 * tn2;
            const int ow = 32 * p + 2 * tm2;
            float* op = out + ((size_t)(b * 64 + k) * 128 + oh) * 128 + ow;
            *(float2*)op         = make_float2(y00, y01);
            *(float2*)(op + 128) = make_float2(y10, y11);
            __syncthreads();   // sM reads done before next kcl write / next patch transform
        }
    }
}

extern "C" void kernel_launch(void* const* d_in, const int* in_sizes, int n_in,
                              void* d_out, int out_size, void* d_ws, size_t ws_size,
                              hipStream_t stream) {
    const float* x    = (const float*)d_in[0];
    const float* w    = (const float*)d_in[1];
    const float* bias = (const float*)d_in[2];
    float* out = (float*)d_out;
    unsigned short* Uf = (unsigned short*)d_ws;   // 256 KB frag-layout U (hi/lo bf16)
    hipFuncSetAttribute((const void*)wg_main, hipFuncAttributeMaxDynamicSharedMemorySize, LDS_BYTES);
    wg_u<<<16, 256, 0, stream>>>(w, Uf);
    wg_main<<<256, 1024, LDS_BYTES, stream>>>(x, Uf, bias, out);
}

// Round 7
// 123.265 us; speedup vs baseline: 1.6810x; 1.6810x over previous
//
#include <hip/hip_runtime.h>
#include <hip/hip_bf16.h>

// Winograd F(2x2,3x3) conv via split-bf16 MFMA. B=8,C=64,K=64 -> out 8x64x128x128 fp32.
// wg_u: U = GwG^T, split hi/lo bf16, d_ws in mfma-A-fragment-linear layout (256KB).
// wg_main: 1024 blocks x 512 thr (8 waves), __launch_bounds__(512,2) -> 256-reg
//   budget (R1/R5/R6 all died on the 128-reg wall: spill -> scratch HBM traffic).
//   Block = 32 tiles (2x16 patch), full K=64, C in 2 chunks of 32.
//   Per chunk: coalesced x load (lane=tile-col) -> B^T d B -> V fp32 in LDS dbuf
//   [16xy][32t][36c] -> barrier -> prefetch next chunk x -> GEMM: wave wv owns
//   xy=2wv,2wv+1; mfma_f32_16x16x32_bf16, D = UhVh+UhVl+UlVh (fp32-grade).
//   Epilogue: sM[16xy][32t][68k] (aliases dbuf), A^T M A + bias, coalesced f2 out.

typedef __attribute__((ext_vector_type(8))) short short8;
typedef __attribute__((ext_vector_type(4))) float f32x4;

#define CPAD 36
#define VSTR (32*CPAD)            // 1152 floats per xy
#define VBUF (16*VSTR)            // 18432 floats per chunk buffer
#define LDS_BYTES (2*VBUF*4)      // 147456 B

__device__ __forceinline__ unsigned short f2bf(float f) {
    unsigned u = __float_as_uint(f);
    unsigned r = (u + 0x7FFF + ((u >> 16) & 1)) >> 16;   // RNE
    return (unsigned short)r;
}

// U frag layout: f = ((xy*2+ks)*4+mt)*2+hl ; ushort[f*512 + lane*8 + j]
// A-frag lane l holds U[k = mt*16 + (l&15)][c = ks*32 + ((l>>4)&3)*8 + j]
__global__ void wg_u(const float* __restrict__ w, unsigned short* __restrict__ Uf) {
    int tid = blockIdx.x * blockDim.x + threadIdx.x;  // 4096 = K*C
    int k = tid & 63, c = tid >> 6;
    const float* wp = w + (k * 64 + c) * 9;
    float g[9];
    #pragma unroll
    for (int i = 0; i < 9; ++i) g[i] = wp[i];
    float t[4][3];
    #pragma unroll
    for (int j = 0; j < 3; ++j) {
        t[0][j] = g[j];
        t[1][j] = 0.5f * (g[j] + g[3 + j] + g[6 + j]);
        t[2][j] = 0.5f * (g[j] - g[3 + j] + g[6 + j]);
        t[3][j] = g[6 + j];
    }
    const int ks   = c >> 5;
    const int mt   = k >> 4;
    const int lane = (k & 15) + 16 * ((c >> 3) & 3);
    const int j    = c & 7;
    #pragma unroll
    for (int xr = 0; xr < 4; ++xr) {
        float a = t[xr][0], b = t[xr][1], cc = t[xr][2];
        float u4[4] = { a, 0.5f * (a + b + cc), 0.5f * (a - b + cc), cc };
        #pragma unroll
        for (int yr = 0; yr < 4; ++yr) {
            int xy = xr * 4 + yr;
            float uv = u4[yr];
            unsigned short h = f2bf(uv);
            float hf = __uint_as_float(((unsigned)h) << 16);
            unsigned short l = f2bf(uv - hf);
            int fh = ((xy * 2 + ks) * 4 + mt) * 2;
            Uf[(fh + 0) * 512 + lane * 8 + j] = h;
            Uf[(fh + 1) * 512 + lane * 8 + j] = l;
        }
    }
}

// cvt 8 fp32 -> bf16 hi/lo frags (pair cvt -> v_cvt_pk_bf16_f32)
__device__ __forceinline__ void cvt_frag(f32x4 a, f32x4 b, short8& h8, short8& l8) {
    union { short8 s; unsigned u[4]; } H, L;
    float v0[4] = { a[0], a[2], b[0], b[2] };
    float v1[4] = { a[1], a[3], b[1], b[3] };
    #pragma unroll
    for (int p = 0; p < 4; ++p) {
        __hip_bfloat162 hb = __float22bfloat162_rn(make_float2(v0[p], v1[p]));
        unsigned hu; __builtin_memcpy(&hu, &hb, 4);
        float h0 = __uint_as_float(hu << 16);
        float h1 = __uint_as_float(hu & 0xFFFF0000u);
        __hip_bfloat162 lb = __float22bfloat162_rn(make_float2(v0[p] - h0, v1[p] - h1));
        unsigned lu; __builtin_memcpy(&lu, &lb, 4);
        H.u[p] = hu; L.u[p] = lu;
    }
    h8 = H.s; l8 = L.s;
}

__global__ __launch_bounds__(512, 2) void wg_main(
    const float* __restrict__ x, const unsigned short* __restrict__ Uf,
    const float* __restrict__ bias, float* __restrict__ out)
{
    extern __shared__ float smem[];   // V dbuf [2][16xy][32t][36c]; sM[16][32][68] aliases

    const int tid  = threadIdx.x;
    const int bx   = blockIdx.x;      // 1024 = b(8) * strip(128)
    const int b    = bx >> 7;
    const int s    = bx & 127;
    const int sr   = s >> 2;          // 0..31 tile-row-pair
    const int sc   = s & 3;           // 0..3  16-tile col group

    const int wv   = tid >> 6;        // 8 waves
    const int lane = tid & 63;
    const int hi   = lane >> 4;       // 0..3
    const int l15  = lane & 15;

    // produce mapping (per uu=0,1): c = wv*4+hi (0..31), tm = l15, tn = uu
    const int pc   = wv * 4 + hi;
    // x base for (c=pc, row=sr*4, col=sc*32+2*l15); chunk adds ch*32*16900, uu adds 2*130
    const float* X0 = x + ((size_t)(b * 64 + pc) * 130 + sr * 4) * 130 + sc * 32 + 2 * l15;

    f32x4 acc[2][4][2];
    #pragma unroll
    for (int e = 0; e < 2; ++e)
        #pragma unroll
        for (int kf = 0; kf < 4; ++kf)
            #pragma unroll
            for (int tf = 0; tf < 2; ++tf) acc[e][kf][tf] = f32x4{0.f, 0.f, 0.f, 0.f};

    // prefetch chunk 0 x
    float2 dn[2][4][2];
    #pragma unroll
    for (int uu = 0; uu < 2; ++uu)
        #pragma unroll
        for (int i = 0; i < 4; ++i) {
            const float* rp = X0 + (2 * uu + i) * 130;
            dn[uu][i][0] = *(const float2*)(rp);
            dn[uu][i][1] = *(const float2*)(rp + 2);
        }

    #pragma unroll
    for (int ch = 0; ch < 2; ++ch) {
        float* Vb = smem + ch * VBUF;
        // ---- transform dn -> V (B^T d B), both units ----
        #pragma unroll
        for (int uu = 0; uu < 2; ++uu) {
            float d[4][4];
            #pragma unroll
            for (int i = 0; i < 4; ++i) {
                d[i][0] = dn[uu][i][0].x; d[i][1] = dn[uu][i][0].y;
                d[i][2] = dn[uu][i][1].x; d[i][3] = dn[uu][i][1].y;
            }
            float s0[4], s1[4], s2[4], s3[4];
            #pragma unroll
            for (int j = 0; j < 4; ++j) {
                s0[j] = d[0][j] - d[2][j];
                s1[j] = d[1][j] + d[2][j];
                s2[j] = d[2][j] - d[1][j];
                s3[j] = d[1][j] - d[3][j];
            }
            const int vo = (uu * 16 + l15) * CPAD + pc;
            #define VROW(X, R)                                    \
                Vb[((X)*4+0)*VSTR + vo] = R[0] - R[2];            \
                Vb[((X)*4+1)*VSTR + vo] = R[1] + R[2];            \
                Vb[((X)*4+2)*VSTR + vo] = R[2] - R[1];            \
                Vb[((X)*4+3)*VSTR + vo] = R[1] - R[3];
            VROW(0, s0) VROW(1, s1) VROW(2, s2) VROW(3, s3)
            #undef VROW
        }
        __syncthreads();
        // ---- prefetch chunk 1 x (covered by GEMM ch0) ----
        if (ch == 0) {
            const float* X1 = X0 + 32 * 16900;
            #pragma unroll
            for (int uu = 0; uu < 2; ++uu)
                #pragma unroll
                for (int i = 0; i < 4; ++i) {
                    const float* rp = X1 + (2 * uu + i) * 130;
                    dn[uu][i][0] = *(const float2*)(rp);
                    dn[uu][i][1] = *(const float2*)(rp + 2);
                }
        }
        // ---- GEMM K-step ch: wave wv owns xy = 2wv, 2wv+1; 48 mfma ----
        #pragma unroll
        for (int e = 0; e < 2; ++e) {
            const int xy = wv * 2 + e;
            const unsigned short* Ab = Uf + ((size_t)((xy * 2 + ch) * 8)) * 512 + lane * 8;
            short8 ah[4], al[4];
            #pragma unroll
            for (int mt = 0; mt < 4; ++mt) {
                ah[mt] = *(const short8*)(Ab + (mt * 2 + 0) * 512);
                al[mt] = *(const short8*)(Ab + (mt * 2 + 1) * 512);
            }
            const float* Bb = Vb + xy * VSTR + l15 * CPAD + hi * 8;
            #pragma unroll
            for (int tf = 0; tf < 2; ++tf) {
                f32x4 p0 = *(const f32x4*)(Bb + tf * 16 * CPAD);
                f32x4 p1 = *(const f32x4*)(Bb + tf * 16 * CPAD + 4);
                short8 bhf, blf;
                cvt_frag(p0, p1, bhf, blf);
                #pragma unroll
                for (int kf = 0; kf < 4; ++kf) {
                    acc[e][kf][tf] = __builtin_amdgcn_mfma_f32_16x16x32_bf16(ah[kf], bhf, acc[e][kf][tf], 0, 0, 0);
                    acc[e][kf][tf] = __builtin_amdgcn_mfma_f32_16x16x32_bf16(ah[kf], blf, acc[e][kf][tf], 0, 0, 0);
                    acc[e][kf][tf] = __builtin_amdgcn_mfma_f32_16x16x32_bf16(al[kf], bhf, acc[e][kf][tf], 0, 0, 0);
                }
            }
        }
        if (ch == 0) __syncthreads();   // GEMM ch0 readers done before... (buf1 writes are
                                        // disjoint, but keeps waves phase-aligned cheaply)
    }

    // ---- epilogue: sM[16 xy][32 t][68 kpad] aliases dbuf ----
    __syncthreads();   // all GEMM ch1 reads of buf1 done before sM overwrite
    float* sM = smem;
    #pragma unroll
    for (int e = 0; e < 2; ++e)
        #pragma unroll
        for (int kf = 0; kf < 4; ++kf)
            #pragma unroll
            for (int tf = 0; tf < 2; ++tf)
                *(f32x4*)(sM + (wv * 2 + e) * 2176 + (tf * 16 + l15) * 68 + kf * 16 + hi * 4)
                    = acc[e][kf][tf];
    __syncthreads();
    #pragma unroll
    for (int p = 0; p < 4; ++p) {
        const int idx = p * 512 + tid;
        const int tt  = idx & 31;
        const int kq  = idx >> 5;
        float m[16];
        #pragma unroll
        for (int xy = 0; xy < 16; ++xy) m[xy] = sM[xy * 2176 + tt * 68 + kq];
        float q0[4], q1[4];
        #pragma unroll
        for (int y = 0; y < 4; ++y) {
            q0[y] = m[y] + m[4 + y] + m[8 + y];
            q1[y] = m[4 + y] - m[8 + y] - m[12 + y];
        }
        const float bv = bias[kq];
        const float y00 = q0[0] + q0[1] + q0[2] + bv;
        const float y01 = q0[1] - q0[2] - q0[3] + bv;
        const float y10 = q1[0] + q1[1] + q1[2] + bv;
        const float y11 = q1[1] - q1[2] - q1[3] + bv;
        const int oh = sr * 4 + 2 * (tt >> 4);
        const int ow = sc * 32 + 2 * (tt & 15);
        float* op = out + ((size_t)(b * 64 + kq) * 128 + oh) * 128 + ow;
        *(float2*)op         = make_float2(y00, y01);
        *(float2*)(op + 128) = make_float2(y10, y11);
    }
}

extern "C" void kernel_launch(void* const* d_in, const int* in_sizes, int n_in,
                              void* d_out, int out_size, void* d_ws, size_t ws_size,
                              hipStream_t stream) {
    const float* x    = (const float*)d_in[0];
    const float* w    = (const float*)d_in[1];
    const float* bias = (const float*)d_in[2];
    float* out = (float*)d_out;
    unsigned short* Uf = (unsigned short*)d_ws;   // 256 KB frag-layout U (hi/lo bf16)
    hipFuncSetAttribute((const void*)wg_main, hipFuncAttributeMaxDynamicSharedMemorySize, LDS_BYTES);
    wg_u<<<16, 256, 0, stream>>>(w, Uf);
    wg_main<<<1024, 512, LDS_BYTES, stream>>>(x, Uf, bias, out);
}